// Round 16
// baseline (901.558 us; speedup 1.0000x reference)
//
#include <hip/hip_runtime.h>
#include <hip/hip_bf16.h>
#include <cstdint>

#define B_ 16
#define N_ 4096
#define CPTS_ 64
#define M_ 1024
#define K_ 32
#define MF_TOT 2097152   // B_*M_*128 pooled outputs
#define NW_ 16384        // B_*M_ waves for fused stats0 partials

using ushort8 = __attribute__((ext_vector_type(8))) unsigned short;
using bf16x8  = __attribute__((ext_vector_type(8))) short;
using f32x4v  = __attribute__((ext_vector_type(4))) float;

static __device__ __forceinline__ unsigned f2bf(float x){
  unsigned u = __float_as_uint(x);
  return (u + 0x7fffu + ((u >> 16) & 1u)) >> 16;   // RTNE
}
static __device__ __forceinline__ float bf2f(unsigned short u){
  return __uint_as_float(((unsigned)u) << 16);
}

// DPP max step: v = max(v, dpp_shift(v)). Values are >= 0 so 0-fill is identity.
#define DPPMAX(v, ctrl)                                                        \
  do {                                                                         \
    int _t = __builtin_amdgcn_update_dpp(0, __float_as_int(v), (ctrl), 0xf,    \
                                         0xf, true);                           \
    (v) = fmaxf((v), __int_as_float(_t));                                      \
  } while (0)

// One distance update, all indices compile-time constant (named float4 comps).
#define STEP(MD, PX, PY, PZ, C, J)                                             \
  { float dx = PX.C - cx, dy = PY.C - cy, dz = PZ.C - cz;                      \
    float d = dx * dx; d = d + dy * dy; d = d + dz * dz;                       \
    float nm = fminf(MD.C, d); MD.C = nm;                                      \
    if (nm > bv){ bv = nm; bj = (J); } }
#define STEP4(MD, PX, PY, PZ, J0)                                              \
  STEP(MD, PX, PY, PZ, x, J0)                                                  \
  STEP(MD, PX, PY, PZ, y, (J0) + 1)                                            \
  STEP(MD, PX, PY, PZ, z, (J0) + 2)                                            \
  STEP(MD, PX, PY, PZ, w, (J0) + 3)

// ---------------- fps (blocks 0..15, R14-verified) + phi (blocks 16..527) ----
// fps occupies 16 CUs for ~640us; phi's 512 independent blocks run
// concurrently on the other ~240 CUs and finish in its shadow.
__global__ __launch_bounds__(256, 1) void fps_phi_kernel(
    const float* __restrict__ xyz, float* __restrict__ newxyz,
    const float* __restrict__ points, const float* __restrict__ W,
    float* __restrict__ phi){
  __shared__ __align__(16) char smem[53760];
  if (blockIdx.x >= 16){
    // ---------------- phi: per-point layer-0 matmul (no gather) -------------
    float* Wt = (float*)smem;               // [67][64]
    float* ft = (float*)(smem + 17152);     // [67][128]
    const int tid = threadIdx.x, blk = blockIdx.x - 16;
    const int p0 = blk * 128;
    for (int i = tid; i < 67 * 64; i += 256){
      int o = i / 67, c = i - o * 67;
      Wt[c * 64 + o] = W[i];
    }
    const int sl = tid >> 1, half = tid & 1;
    const int p = p0 + sl;
    const float* ps = points + (size_t)p * CPTS_ + half * 32;
    #pragma unroll
    for (int j = 0; j < 8; ++j){
      float4 v = *reinterpret_cast<const float4*>(ps + j * 4);
      int c = 3 + half * 32 + j * 4;
      ft[c * 128 + sl] = v.x; ft[(c + 1) * 128 + sl] = v.y;
      ft[(c + 2) * 128 + sl] = v.z; ft[(c + 3) * 128 + sl] = v.w;
    }
    if (half == 0){
      const float* xp = xyz + (size_t)p * 3;
      ft[0 * 128 + sl] = xp[0]; ft[1 * 128 + sl] = xp[1]; ft[2 * 128 + sl] = xp[2];
    }
    __syncthreads();
    const int sg = tid & 31, og = tid >> 5;
    float acc[4][8];
    #pragma unroll
    for (int i = 0; i < 4; ++i)
      #pragma unroll
      for (int o = 0; o < 8; ++o) acc[i][o] = 0.0f;
    #pragma unroll 2
    for (int c = 0; c < 67; ++c){
      float4 f = *reinterpret_cast<const float4*>(&ft[c * 128 + sg * 4]);
      float4 w0 = *reinterpret_cast<const float4*>(&Wt[c * 64 + og * 8]);
      float4 w1 = *reinterpret_cast<const float4*>(&Wt[c * 64 + og * 8 + 4]);
      const float fv[4] = {f.x, f.y, f.z, f.w};
      #pragma unroll
      for (int i = 0; i < 4; ++i){
        acc[i][0] += fv[i] * w0.x; acc[i][1] += fv[i] * w0.y;
        acc[i][2] += fv[i] * w0.z; acc[i][3] += fv[i] * w0.w;
        acc[i][4] += fv[i] * w1.x; acc[i][5] += fv[i] * w1.y;
        acc[i][6] += fv[i] * w1.z; acc[i][7] += fv[i] * w1.w;
      }
    }
    #pragma unroll
    for (int i = 0; i < 4; ++i){
      float* dst = phi + (size_t)(p0 + sg * 4 + i) * 64 + og * 8;
      *reinterpret_cast<float4*>(dst)     = make_float4(acc[i][0], acc[i][1], acc[i][2], acc[i][3]);
      *reinterpret_cast<float4*>(dst + 4) = make_float4(acc[i][4], acc[i][5], acc[i][6], acc[i][7]);
    }
    return;
  }
  // ---------------- fps: R14 body verbatim (4 waves, u64-only exchange) -----
  {
#pragma clang fp contract(off)
    float* xs = (float*)smem;                 // 4096 f
    float* ys = (float*)(smem + 16384);
    float* zs = (float*)(smem + 32768);
    int* inds_s = (int*)(smem + 49152);       // 1024 i
    unsigned long long* sv_ = (unsigned long long*)(smem + 53248);  // [2][4]
    const int b = blockIdx.x, tid = threadIdx.x;
    const int lane = tid & 63, wv = tid >> 6;
    const float* xb = xyz + (size_t)b * N_ * 3;
    for (int i = tid; i < N_ * 3; i += 256){
      float v = xb[i];
      int n = i / 3, c = i - n * 3;
      if (c == 0) xs[n] = v; else if (c == 1) ys[n] = v; else zs[n] = v;
    }
    __syncthreads();
    const float4 px0 = *reinterpret_cast<const float4*>(&xs[tid * 16 + 0]);
    const float4 px1 = *reinterpret_cast<const float4*>(&xs[tid * 16 + 4]);
    const float4 px2 = *reinterpret_cast<const float4*>(&xs[tid * 16 + 8]);
    const float4 px3 = *reinterpret_cast<const float4*>(&xs[tid * 16 + 12]);
    const float4 py0 = *reinterpret_cast<const float4*>(&ys[tid * 16 + 0]);
    const float4 py1 = *reinterpret_cast<const float4*>(&ys[tid * 16 + 4]);
    const float4 py2 = *reinterpret_cast<const float4*>(&ys[tid * 16 + 8]);
    const float4 py3 = *reinterpret_cast<const float4*>(&ys[tid * 16 + 12]);
    const float4 pz0 = *reinterpret_cast<const float4*>(&zs[tid * 16 + 0]);
    const float4 pz1 = *reinterpret_cast<const float4*>(&zs[tid * 16 + 4]);
    const float4 pz2 = *reinterpret_cast<const float4*>(&zs[tid * 16 + 8]);
    const float4 pz3 = *reinterpret_cast<const float4*>(&zs[tid * 16 + 12]);
    float4 md0 = make_float4(1e10f, 1e10f, 1e10f, 1e10f);
    float4 md1 = md0, md2 = md0, md3 = md0;
    int far = 0;
    float cx = xs[0], cy = ys[0], cz = zs[0];
    for (int m = 0; m < M_; ++m){
      if (tid == 0) inds_s[m] = far;
      float bv = -1.0f; int bj = 0;
      STEP4(md0, px0, py0, pz0, 0)
      STEP4(md1, px1, py1, pz1, 4)
      STEP4(md2, px2, py2, pz2, 8)
      STEP4(md3, px3, py3, pz3, 12)
      float wm = bv;
      DPPMAX(wm, 0x111);  // row_shr:1
      DPPMAX(wm, 0x112);  // row_shr:2
      DPPMAX(wm, 0x114);  // row_shr:4
      DPPMAX(wm, 0x118);  // row_shr:8
      DPPMAX(wm, 0x142);  // row_bcast:15
      DPPMAX(wm, 0x143);  // row_bcast:31
      const float wmax = __int_as_float(
          __builtin_amdgcn_readlane(__float_as_int(wm), 63));
      unsigned long long tied = __ballot(bv == wmax);
      const int winlane = (int)__builtin_ctzll(tied);
      const int sl = m & 1;
      if (lane == winlane){
        int wn = tid * 16 + bj;
        sv_[sl * 4 + wv] = ((unsigned long long)__float_as_uint(wmax) << 32)
                         | (unsigned)(4095 - wn);   // (4095-n): smaller n wins on tie
      }
      __syncthreads();
      unsigned long long p0 = sv_[sl * 4 + 0], p1 = sv_[sl * 4 + 1];
      unsigned long long p2 = sv_[sl * 4 + 2], p3 = sv_[sl * 4 + 3];
      if (p1 > p0) p0 = p1;
      if (p3 > p2) p2 = p3;
      if (p2 > p0) p0 = p2;
      far = 4095 - (int)(p0 & 0xffffffffu);
      cx = xs[far]; cy = ys[far]; cz = zs[far];   // broadcast LDS reads
    }
    __syncthreads();
    for (int t = tid; t < M_; t += 256){
      int id = inds_s[t];
      size_t o = ((size_t)b * M_ + t) * 3;
      newxyz[o] = xs[id]; newxyz[o + 1] = ys[id]; newxyz[o + 2] = zs[id];
    }
  }
}

// ---------------- Ball query + fused BN0 stats (blocks 0..4095) -------------
// + psi (blocks 4096..4159). Each query wave mirrors its 32 indices to LDS,
// then lane l = channel l accumulates sum/(sum sq) of (phi[n_k][l] - psi_l),
// psi_l recomputed with the IDENTICAL fmaf expression as the psi array.
__global__ __launch_bounds__(256) void ballq_stats_kernel(
    const float* __restrict__ xyz, const float* __restrict__ newxyz,
    int* __restrict__ gi, float* __restrict__ gif,
    const float* __restrict__ W0, float* __restrict__ psi,
    const float* __restrict__ phi, float* __restrict__ part0){
  if (blockIdx.x >= 4096){
    const int mi = (blockIdx.x - 4096) * 256 + threadIdx.x;
    const float x = newxyz[(size_t)mi * 3];
    const float y = newxyz[(size_t)mi * 3 + 1];
    const float z = newxyz[(size_t)mi * 3 + 2];
    float* dst = psi + (size_t)mi * 64;
    #pragma unroll
    for (int o4 = 0; o4 < 16; ++o4){
      float v[4];
      #pragma unroll
      for (int e = 0; e < 4; ++e){
        int o = o4 * 4 + e;
        v[e] = fmaf(z, W0[o * 67 + 2], fmaf(y, W0[o * 67 + 1], x * W0[o * 67]));
      }
      *reinterpret_cast<float4*>(dst + o4 * 4) = make_float4(v[0], v[1], v[2], v[3]);
    }
    return;
  }
  __shared__ int sidx[4][K_];
  const int wvb = threadIdx.x >> 6;
  const int gw = (blockIdx.x * 256 + threadIdx.x) >> 6;
  const int lane = threadIdx.x & 63;
  const int b = gw >> 10, m = gw & 1023;
  const float* xb = xyz + (size_t)b * N_ * 3;
  const size_t no = (size_t)b * M_ + m;
  const float cx = newxyz[no * 3], cy = newxyz[no * 3 + 1], cz = newxyz[no * 3 + 2];
  const float sm = fmaf(cz, cz, fmaf(cy, cy, cx * cx));
  int total = 0, first_idx = 0; bool havef = false;
  int*   gd = gi  + no * K_;
  float* fd = gif + no * K_;
  for (int ch = 0; ch < 64 && total < K_; ++ch){
    const int n = ch * 64 + lane;
    const float x = xb[n * 3], y = xb[n * 3 + 1], z = xb[n * 3 + 2];
    const float sn = fmaf(z, z, fmaf(y, y, x * x));
    const float dt = fmaf(z, cz, fmaf(y, cy, x * cx));
    float d2 = (sm + sn) - 2.0f * dt;                 // ref: |a|^2+|b|^2-2ab
    float dist = sqrtf(fmaxf(d2, 0.0f));
    bool pred = !(dist > 0.2f);
    unsigned long long mask = __ballot(pred);
    if (!havef && mask){ havef = true; first_idx = ch * 64 + (int)__builtin_ctzll(mask); }
    if (pred){
      int rank = total + (int)__popcll(mask & ((1ull << lane) - 1ull));
      if (rank < K_){ gd[rank] = n; fd[rank] = (float)n; sidx[wvb][rank] = n; }
    }
    total += (int)__popcll(mask);
  }
  if (total < K_ && lane >= total && lane < K_){
    gd[lane] = first_idx; fd[lane] = (float)first_idx; sidx[wvb][lane] = first_idx;
  }
  __syncthreads();
  // fused BN0 partial stats: lane l <-> channel l (64 channels)
  const float wa = W0[lane * 67], wb = W0[lane * 67 + 1], wc = W0[lane * 67 + 2];
  const float psil = fmaf(cz, wc, fmaf(cy, wb, cx * wa));   // == psi[no][lane]
  float sv = 0.f, sq = 0.f;
  const float* pb = phi + (size_t)b * N_ * 64;
  #pragma unroll 8
  for (int k = 0; k < K_; ++k){
    float v = pb[(size_t)sidx[wvb][k] * 64 + lane] - psil;
    sv += v; sq += v * v;
  }
  part0[(size_t)gw * 64 + lane] = sv;
  part0[(size_t)NW_ * 64 + (size_t)gw * 64 + lane] = sq;
}

// ---------------- BN0 stats reduce (row-major [NW][64] partials) ------------
__global__ __launch_bounds__(256) void reduce_stats_rm(const float* __restrict__ pa,
                                                       const float* __restrict__ g,
                                                       const float* __restrict__ bb,
                                                       float* __restrict__ bn, int cout){
  const int ch = blockIdx.x, tid = threadIdx.x;
  float s = 0.f, q = 0.f;
  for (int i = tid; i < NW_; i += 256){
    s += pa[(size_t)i * 64 + ch];
    q += pa[(size_t)NW_ * 64 + (size_t)i * 64 + ch];
  }
  #pragma unroll
  for (int off = 1; off < 64; off <<= 1){ s += __shfl_xor(s, off); q += __shfl_xor(q, off); }
  __shared__ float as_[4], aq_[4];
  if ((tid & 63) == 0){ as_[tid >> 6] = s; aq_[tid >> 6] = q; }
  __syncthreads();
  if (tid == 0){
    float S = as_[0] + as_[1] + as_[2] + as_[3];
    float Q = aq_[0] + aq_[1] + aq_[2] + aq_[3];
    const float cnt = 524288.0f;
    float mean = S / cnt;
    float var  = Q / cnt - mean * mean;
    float sc = g[ch] / sqrtf(var + 1e-5f);
    bn[ch] = sc;
    bn[cout + ch] = bb[ch] - mean * sc;
  }
}

// ---------------- mlp1 via MFMA (split-bf16, 3-term) — R13-verified ---------
__global__ __launch_bounds__(256) void mlp1_mfma(
    const float* __restrict__ phi, const float* __restrict__ psi,
    const int* __restrict__ gi, const float* __restrict__ bn0,
    const float* __restrict__ W1,
    unsigned short* __restrict__ h1, float* __restrict__ part)
{
  __shared__ unsigned short wsh[64 * 72], wsl[64 * 72];
  __shared__ unsigned short fsh[128 * 72], fsl[128 * 72];
  __shared__ int gidx[128];
  __shared__ float psm[4][64];
  const int tid = threadIdx.x, blk = blockIdx.x;
  const size_t s0 = (size_t)blk * 128;
  const int b  = (int)(s0 >> 15);
  const int m0 = ((int)(s0 & 32767)) >> 5;

  for (int i = tid; i < 64 * 64; i += 256){
    int o = i >> 6, c = i & 63;
    float f = W1[i];
    unsigned hb = f2bf(f);
    float res = f - bf2f((unsigned short)hb);
    wsh[o * 72 + c] = (unsigned short)hb;
    wsl[o * 72 + c] = (unsigned short)f2bf(res);
  }
  if (tid < 128) gidx[tid] = gi[(size_t)b * 32768 + (size_t)m0 * K_ + tid];
  psm[tid >> 6][tid & 63] =
      psi[((size_t)b * M_ + m0 + (tid >> 6)) * 64 + (tid & 63)];
  __syncthreads();
  {
    const int sl = tid >> 1, half = tid & 1;
    const int g = gidx[sl];
    const int mi = sl >> 5;
    const float* gp = phi + ((size_t)b * N_ + g) * 64 + half * 32;
    #pragma unroll
    for (int jj = 0; jj < 4; ++jj){
      float4 v0 = *reinterpret_cast<const float4*>(gp + jj * 8);
      float4 v1 = *reinterpret_cast<const float4*>(gp + jj * 8 + 4);
      const float vv[8] = {v0.x, v0.y, v0.z, v0.w, v1.x, v1.y, v1.z, v1.w};
      ushort8 ph, pl;
      #pragma unroll
      for (int e = 0; e < 8; ++e){
        int c = half * 32 + jj * 8 + e;
        float f = fmaxf((vv[e] - psm[mi][c]) * bn0[c] + bn0[64 + c], 0.0f);
        unsigned hb = f2bf(f);
        float res = f - bf2f((unsigned short)hb);
        ph[e] = (unsigned short)hb;
        pl[e] = (unsigned short)f2bf(res);
      }
      *reinterpret_cast<ushort8*>(&fsh[sl * 72 + half * 32 + jj * 8]) = ph;
      *reinterpret_cast<ushort8*>(&fsl[sl * 72 + half * 32 + jj * 8]) = pl;
    }
  }
  __syncthreads();

  const int l = tid & 63, w = tid >> 6;
  const int col = l & 15, g4 = l >> 4;
  const int ch = w * 16 + col;

  bf16x8 bh[2], bl[2];
  #pragma unroll
  for (int ks = 0; ks < 2; ++ks){
    int a = ch * 72 + ks * 32 + g4 * 8;
    bh[ks] = *reinterpret_cast<const bf16x8*>(&wsh[a]);
    bl[ks] = *reinterpret_cast<const bf16x8*>(&wsl[a]);
  }

  f32x4v acc[8];
  #pragma unroll
  for (int st = 0; st < 8; ++st) acc[st] = (f32x4v){0.f, 0.f, 0.f, 0.f};

  #pragma unroll
  for (int st = 0; st < 8; ++st){
    #pragma unroll
    for (int ks = 0; ks < 2; ++ks){
      int a = (st * 16 + col) * 72 + ks * 32 + g4 * 8;
      bf16x8 ah = *reinterpret_cast<const bf16x8*>(&fsh[a]);
      bf16x8 al = *reinterpret_cast<const bf16x8*>(&fsl[a]);
      acc[st] = __builtin_amdgcn_mfma_f32_16x16x32_bf16(ah, bh[ks], acc[st], 0, 0, 0);
      acc[st] = __builtin_amdgcn_mfma_f32_16x16x32_bf16(ah, bl[ks], acc[st], 0, 0, 0);
      acc[st] = __builtin_amdgcn_mfma_f32_16x16x32_bf16(al, bh[ks], acc[st], 0, 0, 0);
    }
  }

  #pragma unroll
  for (int st = 0; st < 8; ++st){
    size_t sbase = s0 + st * 16 + g4 * 4;
    #pragma unroll
    for (int r = 0; r < 4; ++r)
      h1[(sbase + r) * 64 + ch] = (unsigned short)f2bf(acc[st][r]);
  }

  float sv = 0.f, sq = 0.f;
  #pragma unroll
  for (int st = 0; st < 8; ++st){
    f32x4v a = acc[st];
    float t0 = a[0], t1 = a[1], t2 = a[2], t3 = a[3];
    sv += ((t0 + t1) + t2) + t3;
    sq += ((t0 * t0 + t1 * t1) + t2 * t2) + t3 * t3;
  }
  sv += __shfl_xor(sv, 16); sv += __shfl_xor(sv, 32);
  sq += __shfl_xor(sq, 16); sq += __shfl_xor(sq, 32);
  if (g4 == 0){
    part[(size_t)(ch * 2) * 4096 + blk]     = sv;
    part[(size_t)(ch * 2 + 1) * 4096 + blk] = sq;
  }
}

// ---------------- mlp2 via MFMA (split-bf16, 3-term) — R12-verified ---------
__global__ __launch_bounds__(256) void mlp2_mfma(
    const unsigned short* __restrict__ h1, const float* __restrict__ bn1,
    const float* __restrict__ W2, float* __restrict__ part,
    float* __restrict__ mxmn)
{
  __shared__ unsigned short wsh[128 * 72], wsl[128 * 72];
  __shared__ unsigned short fsh[128 * 72], fsl[128 * 72];
  const int tid = threadIdx.x, blk = blockIdx.x;
  const size_t s0 = (size_t)blk * 128;

  for (int i = tid; i < 128 * 64; i += 256){
    int o = i >> 6, c = i & 63;
    float f = W2[i];
    unsigned hb = f2bf(f);
    float res = f - bf2f((unsigned short)hb);
    wsh[o * 72 + c] = (unsigned short)hb;
    wsl[o * 72 + c] = (unsigned short)f2bf(res);
  }
  {
    const int sl = tid >> 1, c0 = (tid & 1) * 32;
    const unsigned short* hp = h1 + (s0 + sl) * 64 + c0;
    #pragma unroll
    for (int j = 0; j < 4; ++j){
      ushort8 raw = *reinterpret_cast<const ushort8*>(hp + j * 8);
      ushort8 ph, pl;
      #pragma unroll
      for (int e = 0; e < 8; ++e){
        int c = c0 + j * 8 + e;
        float f = fmaxf(bf2f(raw[e]) * bn1[c] + bn1[64 + c], 0.0f);
        unsigned hb = f2bf(f);
        float res = f - bf2f((unsigned short)hb);
        ph[e] = (unsigned short)hb;
        pl[e] = (unsigned short)f2bf(res);
      }
      *reinterpret_cast<ushort8*>(&fsh[sl * 72 + c0 + j * 8]) = ph;
      *reinterpret_cast<ushort8*>(&fsl[sl * 72 + c0 + j * 8]) = pl;
    }
  }
  __syncthreads();

  const int l = tid & 63, w = tid >> 6;
  const int col = l & 15, g = l >> 4;

  bf16x8 bh[2][2], bl[2][2];
  #pragma unroll
  for (int ot = 0; ot < 2; ++ot)
    #pragma unroll
    for (int ks = 0; ks < 2; ++ks){
      int a = (w * 32 + ot * 16 + col) * 72 + ks * 32 + g * 8;
      bh[ot][ks] = *reinterpret_cast<const bf16x8*>(&wsh[a]);
      bl[ot][ks] = *reinterpret_cast<const bf16x8*>(&wsl[a]);
    }

  f32x4v acc[8][2];
  #pragma unroll
  for (int st = 0; st < 8; ++st)
    #pragma unroll
    for (int ot = 0; ot < 2; ++ot)
      acc[st][ot] = (f32x4v){0.f, 0.f, 0.f, 0.f};

  #pragma unroll
  for (int st = 0; st < 8; ++st){
    bf16x8 ah[2], al[2];
    #pragma unroll
    for (int ks = 0; ks < 2; ++ks){
      int a = (st * 16 + col) * 72 + ks * 32 + g * 8;
      ah[ks] = *reinterpret_cast<const bf16x8*>(&fsh[a]);
      al[ks] = *reinterpret_cast<const bf16x8*>(&fsl[a]);
    }
    #pragma unroll
    for (int ot = 0; ot < 2; ++ot){
      #pragma unroll
      for (int ks = 0; ks < 2; ++ks){
        acc[st][ot] = __builtin_amdgcn_mfma_f32_16x16x32_bf16(ah[ks], bh[ot][ks], acc[st][ot], 0, 0, 0);
        acc[st][ot] = __builtin_amdgcn_mfma_f32_16x16x32_bf16(ah[ks], bl[ot][ks], acc[st][ot], 0, 0, 0);
        acc[st][ot] = __builtin_amdgcn_mfma_f32_16x16x32_bf16(al[ks], bh[ot][ks], acc[st][ot], 0, 0, 0);
      }
    }
  }

  #pragma unroll
  for (int ot = 0; ot < 2; ++ot){
    const int ch = w * 32 + ot * 16 + col;
    float sv = 0.f, sq = 0.f;
    float mxm[4], mnm[4];
    #pragma unroll
    for (int j = 0; j < 4; ++j){ mxm[j] = -1e30f; mnm[j] = 1e30f; }
    #pragma unroll
    for (int st = 0; st < 8; ++st){
      f32x4v a = acc[st][ot];
      float t0 = a[0], t1 = a[1], t2 = a[2], t3 = a[3];
      sv += ((t0 + t1) + t2) + t3;
      sq += ((t0 * t0 + t1 * t1) + t2 * t2) + t3 * t3;
      float tmx = fmaxf(fmaxf(t0, t1), fmaxf(t2, t3));
      float tmn = fminf(fminf(t0, t1), fminf(t2, t3));
      mxm[st >> 1] = fmaxf(mxm[st >> 1], tmx);
      mnm[st >> 1] = fminf(mnm[st >> 1], tmn);
    }
    sv += __shfl_xor(sv, 16); sv += __shfl_xor(sv, 32);
    sq += __shfl_xor(sq, 16); sq += __shfl_xor(sq, 32);
    #pragma unroll
    for (int j = 0; j < 4; ++j){
      mxm[j] = fmaxf(mxm[j], __shfl_xor(mxm[j], 16));
      mxm[j] = fmaxf(mxm[j], __shfl_xor(mxm[j], 32));
      mnm[j] = fminf(mnm[j], __shfl_xor(mnm[j], 16));
      mnm[j] = fminf(mnm[j], __shfl_xor(mnm[j], 32));
    }
    if (g == 0){
      part[(size_t)(ch * 2) * 4096 + blk]     = sv;
      part[(size_t)(ch * 2 + 1) * 4096 + blk] = sq;
      #pragma unroll
      for (int j = 0; j < 4; ++j){
        size_t mf = (s0 >> 5) + j;
        mxmn[mf * 128 + ch]          = mxm[j];
        mxmn[MF_TOT + mf * 128 + ch] = mnm[j];
      }
    }
  }
}

// ---------------- BN stats reduce (legacy [ch*2][4096] partials) ------------
__global__ __launch_bounds__(256) void reduce_stats(const float* __restrict__ part,
                                                    const float* __restrict__ g,
                                                    const float* __restrict__ bb,
                                                    float* __restrict__ bn, int cout){
  const int ch = blockIdx.x, tid = threadIdx.x;
  float s = 0.f, q = 0.f;
  const float* ps = part + (size_t)(ch * 2) * 4096;
  const float* pq = part + (size_t)(ch * 2 + 1) * 4096;
  for (int i = tid; i < 4096; i += 256){ s += ps[i]; q += pq[i]; }
  #pragma unroll
  for (int off = 1; off < 64; off <<= 1){ s += __shfl_xor(s, off); q += __shfl_xor(q, off); }
  __shared__ float as_[4], aq_[4];
  if ((tid & 63) == 0){ as_[tid >> 6] = s; aq_[tid >> 6] = q; }
  __syncthreads();
  if (tid == 0){
    float S = as_[0] + as_[1] + as_[2] + as_[3];
    float Q = aq_[0] + aq_[1] + aq_[2] + aq_[3];
    const float cnt = 524288.0f;
    float mean = S / cnt;
    float var  = Q / cnt - mean * mean;
    float sc = g[ch] / sqrtf(var + 1e-5f);
    bn[ch] = sc;
    bn[cout + ch] = bb[ch] - mean * sc;
  }
}

// ---------------- finish: out = relu(max(a*mx+sh, a*mn+sh)) -----------------
__global__ __launch_bounds__(256) void bn_minmax_finish(const float* __restrict__ mxmn,
                                                        const float* __restrict__ bn2,
                                                        float* __restrict__ out){
  const int i = blockIdx.x * 256 + threadIdx.x;
  const int ch = i & 127;
  const float a = bn2[ch], sh = bn2[128 + ch];
  const float mx = mxmn[i], mn = mxmn[MF_TOT + i];
  out[i] = fmaxf(fmaxf(mx * a + sh, mn * a + sh), 0.0f);
}

extern "C" void kernel_launch(void* const* d_in, const int* in_sizes, int n_in,
                              void* d_out, int out_size, void* d_ws, size_t ws_size,
                              hipStream_t stream){
  (void)in_sizes; (void)n_in; (void)out_size; (void)ws_size;
  const float* xyz    = (const float*)d_in[0];
  const float* points = (const float*)d_in[1];
  const float* W0 = (const float*)d_in[2];
  const float* g0 = (const float*)d_in[3];
  const float* b0 = (const float*)d_in[4];
  const float* W1 = (const float*)d_in[5];
  const float* g1 = (const float*)d_in[6];
  const float* b1 = (const float*)d_in[7];
  const float* W2 = (const float*)d_in[8];
  const float* g2 = (const float*)d_in[9];
  const float* b2 = (const float*)d_in[10];

  float* out = (float*)d_out;
  float* o_newxyz = out;
  float* o_newpts = out + (size_t)B_ * M_ * 3;
  float* o_gind   = out + (size_t)B_ * M_ * 3 + (size_t)B_ * M_ * 128;

  char* ws = (char*)d_ws;
  int*   gi   = (int*)(ws + 0);                          // 2 MB
  float* part = (float*)(ws + (2ull << 20));             // 4 MB (layers 1/2)
  float* bn0  = (float*)(ws + (6ull << 20));
  float* bn1  = (float*)(ws + (6ull << 20) + 1024);
  float* bn2  = (float*)(ws + (6ull << 20) + 2048);
  float* phi  = (float*)(ws + (8ull << 20));             // 16 MB
  float* psi  = (float*)(ws + (24ull << 20));            // 4 MB
  unsigned short* h1 = (unsigned short*)(ws + (28ull << 20));   // 64 MB
  float* mxmn = (float*)(ws + (92ull << 20));            // 16 MB
  float* part0 = (float*)(ws + (108ull << 20));          // 8 MB (layer-0 stats)

  fps_phi_kernel<<<528, 256, 0, stream>>>(xyz, o_newxyz, points, W0, phi);
  ballq_stats_kernel<<<4160, 256, 0, stream>>>(xyz, o_newxyz, gi, o_gind,
                                               W0, psi, phi, part0);
  reduce_stats_rm<<<64, 256, 0, stream>>>(part0, g0, b0, bn0, 64);

  mlp1_mfma<<<4096, 256, 0, stream>>>(phi, psi, gi, bn0, W1, h1, part);
  reduce_stats<<<64, 256, 0, stream>>>(part, g1, b1, bn1, 64);

  mlp2_mfma<<<4096, 256, 0, stream>>>(h1, bn1, W2, part, mxmn);
  reduce_stats<<<128, 256, 0, stream>>>(part, g2, b2, bn2, 128);
  bn_minmax_finish<<<MF_TOT / 256, 256, 0, stream>>>(mxmn, bn2, o_newpts);
}

// Round 17
// 895.555 us; speedup vs baseline: 1.0067x; 1.0067x over previous
//
#include <hip/hip_runtime.h>
#include <hip/hip_bf16.h>
#include <cstdint>

#define B_ 16
#define N_ 4096
#define CPTS_ 64
#define M_ 1024
#define K_ 32
#define MF_TOT 2097152   // B_*M_*128 pooled outputs
#define NW_ 16384        // B_*M_ waves for fused stats0 partials

using ushort8 = __attribute__((ext_vector_type(8))) unsigned short;
using bf16x8  = __attribute__((ext_vector_type(8))) short;
using f32x4v  = __attribute__((ext_vector_type(4))) float;

static __device__ __forceinline__ unsigned f2bf(float x){
  unsigned u = __float_as_uint(x);
  return (u + 0x7fffu + ((u >> 16) & 1u)) >> 16;   // RTNE
}
static __device__ __forceinline__ float bf2f(unsigned short u){
  return __uint_as_float(((unsigned)u) << 16);
}

// DPP max step: v = max(v, dpp_shift(v)). Values are >= 0 so 0-fill is identity.
#define DPPMAX(v, ctrl)                                                        \
  do {                                                                         \
    int _t = __builtin_amdgcn_update_dpp(0, __float_as_int(v), (ctrl), 0xf,    \
                                         0xf, true);                           \
    (v) = fmaxf((v), __int_as_float(_t));                                      \
  } while (0)

// One distance update, all indices compile-time constant (named float4 comps).
#define STEP(MD, PX, PY, PZ, C, J)                                             \
  { float dx = PX.C - cx, dy = PY.C - cy, dz = PZ.C - cz;                      \
    float d = dx * dx; d = d + dy * dy; d = d + dz * dz;                       \
    float nm = fminf(MD.C, d); MD.C = nm;                                      \
    if (nm > bv){ bv = nm; bj = (J); } }
#define STEP4(MD, PX, PY, PZ, J0)                                              \
  STEP(MD, PX, PY, PZ, x, J0)                                                  \
  STEP(MD, PX, PY, PZ, y, (J0) + 1)                                            \
  STEP(MD, PX, PY, PZ, z, (J0) + 2)                                            \
  STEP(MD, PX, PY, PZ, w, (J0) + 3)

// ---------------- FPS: R14 standalone verbatim (641 us, proven floor) -------
// R16's merged fps+phi kernel regressed fps 641->668 (smem pointer-cast union
// + branch perturbed scheduling). Standalone with declared __shared__ wins.
__global__ __launch_bounds__(256, 1) void fps_kernel(const float* __restrict__ xyz,
                                                     float* __restrict__ newxyz){
#pragma clang fp contract(off)
  __shared__ float xs[N_], ys[N_], zs[N_];
  __shared__ int inds_s[M_];
  __shared__ unsigned long long sv_[2][4];
  const int b = blockIdx.x, tid = threadIdx.x;
  const int lane = tid & 63, wv = tid >> 6;
  const float* xb = xyz + (size_t)b * N_ * 3;
  for (int i = tid; i < N_ * 3; i += 256){
    float v = xb[i];
    int n = i / 3, c = i - n * 3;
    if (c == 0) xs[n] = v; else if (c == 1) ys[n] = v; else zs[n] = v;
  }
  __syncthreads();
  // per-lane points: n = tid*16 + j  (wave w owns [w*1024, w*1024+1024))
  const float4 px0 = *reinterpret_cast<const float4*>(&xs[tid * 16 + 0]);
  const float4 px1 = *reinterpret_cast<const float4*>(&xs[tid * 16 + 4]);
  const float4 px2 = *reinterpret_cast<const float4*>(&xs[tid * 16 + 8]);
  const float4 px3 = *reinterpret_cast<const float4*>(&xs[tid * 16 + 12]);
  const float4 py0 = *reinterpret_cast<const float4*>(&ys[tid * 16 + 0]);
  const float4 py1 = *reinterpret_cast<const float4*>(&ys[tid * 16 + 4]);
  const float4 py2 = *reinterpret_cast<const float4*>(&ys[tid * 16 + 8]);
  const float4 py3 = *reinterpret_cast<const float4*>(&ys[tid * 16 + 12]);
  const float4 pz0 = *reinterpret_cast<const float4*>(&zs[tid * 16 + 0]);
  const float4 pz1 = *reinterpret_cast<const float4*>(&zs[tid * 16 + 4]);
  const float4 pz2 = *reinterpret_cast<const float4*>(&zs[tid * 16 + 8]);
  const float4 pz3 = *reinterpret_cast<const float4*>(&zs[tid * 16 + 12]);
  float4 md0 = make_float4(1e10f, 1e10f, 1e10f, 1e10f);
  float4 md1 = md0, md2 = md0, md3 = md0;
  int far = 0;
  float cx = xs[0], cy = ys[0], cz = zs[0];
  for (int m = 0; m < M_; ++m){
    if (tid == 0) inds_s[m] = far;
    float bv = -1.0f; int bj = 0;
    STEP4(md0, px0, py0, pz0, 0)
    STEP4(md1, px1, py1, pz1, 4)
    STEP4(md2, px2, py2, pz2, 8)
    STEP4(md3, px3, py3, pz3, 12)
    // in-wave max via DPP (VALU, no LDS): result in lane 63
    float wm = bv;
    DPPMAX(wm, 0x111);  // row_shr:1
    DPPMAX(wm, 0x112);  // row_shr:2
    DPPMAX(wm, 0x114);  // row_shr:4
    DPPMAX(wm, 0x118);  // row_shr:8
    DPPMAX(wm, 0x142);  // row_bcast:15
    DPPMAX(wm, 0x143);  // row_bcast:31
    const float wmax = __int_as_float(
        __builtin_amdgcn_readlane(__float_as_int(wm), 63));
    // lowest tied lane = smallest n (lane ascending == n ascending per wave)
    unsigned long long tied = __ballot(bv == wmax);
    const int winlane = (int)__builtin_ctzll(tied);
    const int sl = m & 1;
    if (lane == winlane){
      int wn = tid * 16 + bj;
      sv_[sl][wv] = ((unsigned long long)__float_as_uint(wmax) << 32)
                  | (unsigned)(4095 - wn);     // (4095-n): smaller n wins on tie
    }
    __syncthreads();
    // 4-slot max tree; all pk distinct (distinct indices) => total order
    unsigned long long p0 = sv_[sl][0], p1 = sv_[sl][1], p2 = sv_[sl][2], p3 = sv_[sl][3];
    if (p1 > p0) p0 = p1;
    if (p3 > p2) p2 = p3;
    if (p2 > p0) p0 = p2;
    far = 4095 - (int)(p0 & 0xffffffffu);
    cx = xs[far]; cy = ys[far]; cz = zs[far];   // broadcast LDS reads
  }
  __syncthreads();
  for (int t = tid; t < M_; t += 256){
    int id = inds_s[t];
    size_t o = ((size_t)b * M_ + t) * 3;
    newxyz[o] = xs[id]; newxyz[o + 1] = ys[id]; newxyz[o + 2] = zs[id];
  }
}

// ---------------- phi: per-point layer-0 matmul (no gather, R14 verbatim) ---
__global__ __launch_bounds__(256) void phi_kernel(const float* __restrict__ xyz,
                                                  const float* __restrict__ points,
                                                  const float* __restrict__ W,
                                                  float* __restrict__ phi){
  __shared__ __align__(16) float Wt[67][64];
  __shared__ __align__(16) float ft[67][128];
  const int tid = threadIdx.x, blk = blockIdx.x;
  const int p0 = blk * 128;
  for (int i = tid; i < 67 * 64; i += 256){
    int o = i / 67, c = i - o * 67;
    Wt[c][o] = W[i];
  }
  const int sl = tid >> 1, half = tid & 1;
  const int p = p0 + sl;
  const float* ps = points + (size_t)p * CPTS_ + half * 32;
  #pragma unroll
  for (int j = 0; j < 8; ++j){
    float4 v = *reinterpret_cast<const float4*>(ps + j * 4);
    int c = 3 + half * 32 + j * 4;
    ft[c][sl] = v.x; ft[c + 1][sl] = v.y; ft[c + 2][sl] = v.z; ft[c + 3][sl] = v.w;
  }
  if (half == 0){
    const float* xp = xyz + (size_t)p * 3;
    ft[0][sl] = xp[0]; ft[1][sl] = xp[1]; ft[2][sl] = xp[2];
  }
  __syncthreads();
  const int sg = tid & 31, og = tid >> 5;
  float acc[4][8];
  #pragma unroll
  for (int i = 0; i < 4; ++i)
    #pragma unroll
    for (int o = 0; o < 8; ++o) acc[i][o] = 0.0f;
  #pragma unroll 2
  for (int c = 0; c < 67; ++c){
    float4 f = *reinterpret_cast<const float4*>(&ft[c][sg * 4]);
    float4 w0 = *reinterpret_cast<const float4*>(&Wt[c][og * 8]);
    float4 w1 = *reinterpret_cast<const float4*>(&Wt[c][og * 8 + 4]);
    const float fv[4] = {f.x, f.y, f.z, f.w};
    #pragma unroll
    for (int i = 0; i < 4; ++i){
      acc[i][0] += fv[i] * w0.x; acc[i][1] += fv[i] * w0.y;
      acc[i][2] += fv[i] * w0.z; acc[i][3] += fv[i] * w0.w;
      acc[i][4] += fv[i] * w1.x; acc[i][5] += fv[i] * w1.y;
      acc[i][6] += fv[i] * w1.z; acc[i][7] += fv[i] * w1.w;
    }
  }
  #pragma unroll
  for (int i = 0; i < 4; ++i){
    float* dst = phi + (size_t)(p0 + sg * 4 + i) * 64 + og * 8;
    *reinterpret_cast<float4*>(dst)     = make_float4(acc[i][0], acc[i][1], acc[i][2], acc[i][3]);
    *reinterpret_cast<float4*>(dst + 4) = make_float4(acc[i][4], acc[i][5], acc[i][6], acc[i][7]);
  }
}

// ---------------- Ball query + fused BN0 stats (R16-verified) ---------------
__global__ __launch_bounds__(256) void ballq_stats_kernel(
    const float* __restrict__ xyz, const float* __restrict__ newxyz,
    int* __restrict__ gi, float* __restrict__ gif,
    const float* __restrict__ W0, float* __restrict__ psi,
    const float* __restrict__ phi, float* __restrict__ part0){
  if (blockIdx.x >= 4096){
    const int mi = (blockIdx.x - 4096) * 256 + threadIdx.x;
    const float x = newxyz[(size_t)mi * 3];
    const float y = newxyz[(size_t)mi * 3 + 1];
    const float z = newxyz[(size_t)mi * 3 + 2];
    float* dst = psi + (size_t)mi * 64;
    #pragma unroll
    for (int o4 = 0; o4 < 16; ++o4){
      float v[4];
      #pragma unroll
      for (int e = 0; e < 4; ++e){
        int o = o4 * 4 + e;
        v[e] = fmaf(z, W0[o * 67 + 2], fmaf(y, W0[o * 67 + 1], x * W0[o * 67]));
      }
      *reinterpret_cast<float4*>(dst + o4 * 4) = make_float4(v[0], v[1], v[2], v[3]);
    }
    return;
  }
  __shared__ int sidx[4][K_];
  const int wvb = threadIdx.x >> 6;
  const int gw = (blockIdx.x * 256 + threadIdx.x) >> 6;
  const int lane = threadIdx.x & 63;
  const int b = gw >> 10, m = gw & 1023;
  const float* xb = xyz + (size_t)b * N_ * 3;
  const size_t no = (size_t)b * M_ + m;
  const float cx = newxyz[no * 3], cy = newxyz[no * 3 + 1], cz = newxyz[no * 3 + 2];
  const float sm = fmaf(cz, cz, fmaf(cy, cy, cx * cx));
  int total = 0, first_idx = 0; bool havef = false;
  int*   gd = gi  + no * K_;
  float* fd = gif + no * K_;
  for (int ch = 0; ch < 64 && total < K_; ++ch){
    const int n = ch * 64 + lane;
    const float x = xb[n * 3], y = xb[n * 3 + 1], z = xb[n * 3 + 2];
    const float sn = fmaf(z, z, fmaf(y, y, x * x));
    const float dt = fmaf(z, cz, fmaf(y, cy, x * cx));
    float d2 = (sm + sn) - 2.0f * dt;                 // ref: |a|^2+|b|^2-2ab
    float dist = sqrtf(fmaxf(d2, 0.0f));
    bool pred = !(dist > 0.2f);
    unsigned long long mask = __ballot(pred);
    if (!havef && mask){ havef = true; first_idx = ch * 64 + (int)__builtin_ctzll(mask); }
    if (pred){
      int rank = total + (int)__popcll(mask & ((1ull << lane) - 1ull));
      if (rank < K_){ gd[rank] = n; fd[rank] = (float)n; sidx[wvb][rank] = n; }
    }
    total += (int)__popcll(mask);
  }
  if (total < K_ && lane >= total && lane < K_){
    gd[lane] = first_idx; fd[lane] = (float)first_idx; sidx[wvb][lane] = first_idx;
  }
  __syncthreads();
  // fused BN0 partial stats: lane l <-> channel l (64 channels)
  const float wa = W0[lane * 67], wb = W0[lane * 67 + 1], wc = W0[lane * 67 + 2];
  const float psil = fmaf(cz, wc, fmaf(cy, wb, cx * wa));   // == psi[no][lane]
  float sv = 0.f, sq = 0.f;
  const float* pb = phi + (size_t)b * N_ * 64;
  #pragma unroll 8
  for (int k = 0; k < K_; ++k){
    float v = pb[(size_t)sidx[wvb][k] * 64 + lane] - psil;
    sv += v; sq += v * v;
  }
  part0[(size_t)gw * 64 + lane] = sv;
  part0[(size_t)NW_ * 64 + (size_t)gw * 64 + lane] = sq;
}

// ---------------- BN0 stats reduce (row-major [NW][64] partials) ------------
__global__ __launch_bounds__(256) void reduce_stats_rm(const float* __restrict__ pa,
                                                       const float* __restrict__ g,
                                                       const float* __restrict__ bb,
                                                       float* __restrict__ bn, int cout){
  const int ch = blockIdx.x, tid = threadIdx.x;
  float s = 0.f, q = 0.f;
  for (int i = tid; i < NW_; i += 256){
    s += pa[(size_t)i * 64 + ch];
    q += pa[(size_t)NW_ * 64 + (size_t)i * 64 + ch];
  }
  #pragma unroll
  for (int off = 1; off < 64; off <<= 1){ s += __shfl_xor(s, off); q += __shfl_xor(q, off); }
  __shared__ float as_[4], aq_[4];
  if ((tid & 63) == 0){ as_[tid >> 6] = s; aq_[tid >> 6] = q; }
  __syncthreads();
  if (tid == 0){
    float S = as_[0] + as_[1] + as_[2] + as_[3];
    float Q = aq_[0] + aq_[1] + aq_[2] + aq_[3];
    const float cnt = 524288.0f;
    float mean = S / cnt;
    float var  = Q / cnt - mean * mean;
    float sc = g[ch] / sqrtf(var + 1e-5f);
    bn[ch] = sc;
    bn[cout + ch] = bb[ch] - mean * sc;
  }
}

// ---------------- mlp1 via MFMA (split-bf16, 3-term) — R13-verified ---------
__global__ __launch_bounds__(256) void mlp1_mfma(
    const float* __restrict__ phi, const float* __restrict__ psi,
    const int* __restrict__ gi, const float* __restrict__ bn0,
    const float* __restrict__ W1,
    unsigned short* __restrict__ h1, float* __restrict__ part)
{
  __shared__ unsigned short wsh[64 * 72], wsl[64 * 72];
  __shared__ unsigned short fsh[128 * 72], fsl[128 * 72];
  __shared__ int gidx[128];
  __shared__ float psm[4][64];
  const int tid = threadIdx.x, blk = blockIdx.x;
  const size_t s0 = (size_t)blk * 128;
  const int b  = (int)(s0 >> 15);
  const int m0 = ((int)(s0 & 32767)) >> 5;

  for (int i = tid; i < 64 * 64; i += 256){
    int o = i >> 6, c = i & 63;
    float f = W1[i];
    unsigned hb = f2bf(f);
    float res = f - bf2f((unsigned short)hb);
    wsh[o * 72 + c] = (unsigned short)hb;
    wsl[o * 72 + c] = (unsigned short)f2bf(res);
  }
  if (tid < 128) gidx[tid] = gi[(size_t)b * 32768 + (size_t)m0 * K_ + tid];
  psm[tid >> 6][tid & 63] =
      psi[((size_t)b * M_ + m0 + (tid >> 6)) * 64 + (tid & 63)];
  __syncthreads();
  {
    const int sl = tid >> 1, half = tid & 1;
    const int g = gidx[sl];
    const int mi = sl >> 5;
    const float* gp = phi + ((size_t)b * N_ + g) * 64 + half * 32;
    #pragma unroll
    for (int jj = 0; jj < 4; ++jj){
      float4 v0 = *reinterpret_cast<const float4*>(gp + jj * 8);
      float4 v1 = *reinterpret_cast<const float4*>(gp + jj * 8 + 4);
      const float vv[8] = {v0.x, v0.y, v0.z, v0.w, v1.x, v1.y, v1.z, v1.w};
      ushort8 ph, pl;
      #pragma unroll
      for (int e = 0; e < 8; ++e){
        int c = half * 32 + jj * 8 + e;
        float f = fmaxf((vv[e] - psm[mi][c]) * bn0[c] + bn0[64 + c], 0.0f);
        unsigned hb = f2bf(f);
        float res = f - bf2f((unsigned short)hb);
        ph[e] = (unsigned short)hb;
        pl[e] = (unsigned short)f2bf(res);
      }
      *reinterpret_cast<ushort8*>(&fsh[sl * 72 + half * 32 + jj * 8]) = ph;
      *reinterpret_cast<ushort8*>(&fsl[sl * 72 + half * 32 + jj * 8]) = pl;
    }
  }
  __syncthreads();

  const int l = tid & 63, w = tid >> 6;
  const int col = l & 15, g4 = l >> 4;
  const int ch = w * 16 + col;

  bf16x8 bh[2], bl[2];
  #pragma unroll
  for (int ks = 0; ks < 2; ++ks){
    int a = ch * 72 + ks * 32 + g4 * 8;
    bh[ks] = *reinterpret_cast<const bf16x8*>(&wsh[a]);
    bl[ks] = *reinterpret_cast<const bf16x8*>(&wsl[a]);
  }

  f32x4v acc[8];
  #pragma unroll
  for (int st = 0; st < 8; ++st) acc[st] = (f32x4v){0.f, 0.f, 0.f, 0.f};

  #pragma unroll
  for (int st = 0; st < 8; ++st){
    #pragma unroll
    for (int ks = 0; ks < 2; ++ks){
      int a = (st * 16 + col) * 72 + ks * 32 + g4 * 8;
      bf16x8 ah = *reinterpret_cast<const bf16x8*>(&fsh[a]);
      bf16x8 al = *reinterpret_cast<const bf16x8*>(&fsl[a]);
      acc[st] = __builtin_amdgcn_mfma_f32_16x16x32_bf16(ah, bh[ks], acc[st], 0, 0, 0);
      acc[st] = __builtin_amdgcn_mfma_f32_16x16x32_bf16(ah, bl[ks], acc[st], 0, 0, 0);
      acc[st] = __builtin_amdgcn_mfma_f32_16x16x32_bf16(al, bh[ks], acc[st], 0, 0, 0);
    }
  }

  #pragma unroll
  for (int st = 0; st < 8; ++st){
    size_t sbase = s0 + st * 16 + g4 * 4;
    #pragma unroll
    for (int r = 0; r < 4; ++r)
      h1[(sbase + r) * 64 + ch] = (unsigned short)f2bf(acc[st][r]);
  }

  float sv = 0.f, sq = 0.f;
  #pragma unroll
  for (int st = 0; st < 8; ++st){
    f32x4v a = acc[st];
    float t0 = a[0], t1 = a[1], t2 = a[2], t3 = a[3];
    sv += ((t0 + t1) + t2) + t3;
    sq += ((t0 * t0 + t1 * t1) + t2 * t2) + t3 * t3;
  }
  sv += __shfl_xor(sv, 16); sv += __shfl_xor(sv, 32);
  sq += __shfl_xor(sq, 16); sq += __shfl_xor(sq, 32);
  if (g4 == 0){
    part[(size_t)(ch * 2) * 4096 + blk]     = sv;
    part[(size_t)(ch * 2 + 1) * 4096 + blk] = sq;
  }
}

// ---------------- mlp2 via MFMA (split-bf16, 3-term) — R12-verified ---------
__global__ __launch_bounds__(256) void mlp2_mfma(
    const unsigned short* __restrict__ h1, const float* __restrict__ bn1,
    const float* __restrict__ W2, float* __restrict__ part,
    float* __restrict__ mxmn)
{
  __shared__ unsigned short wsh[128 * 72], wsl[128 * 72];
  __shared__ unsigned short fsh[128 * 72], fsl[128 * 72];
  const int tid = threadIdx.x, blk = blockIdx.x;
  const size_t s0 = (size_t)blk * 128;

  for (int i = tid; i < 128 * 64; i += 256){
    int o = i >> 6, c = i & 63;
    float f = W2[i];
    unsigned hb = f2bf(f);
    float res = f - bf2f((unsigned short)hb);
    wsh[o * 72 + c] = (unsigned short)hb;
    wsl[o * 72 + c] = (unsigned short)f2bf(res);
  }
  {
    const int sl = tid >> 1, c0 = (tid & 1) * 32;
    const unsigned short* hp = h1 + (s0 + sl) * 64 + c0;
    #pragma unroll
    for (int j = 0; j < 4; ++j){
      ushort8 raw = *reinterpret_cast<const ushort8*>(hp + j * 8);
      ushort8 ph, pl;
      #pragma unroll
      for (int e = 0; e < 8; ++e){
        int c = c0 + j * 8 + e;
        float f = fmaxf(bf2f(raw[e]) * bn1[c] + bn1[64 + c], 0.0f);
        unsigned hb = f2bf(f);
        float res = f - bf2f((unsigned short)hb);
        ph[e] = (unsigned short)hb;
        pl[e] = (unsigned short)f2bf(res);
      }
      *reinterpret_cast<ushort8*>(&fsh[sl * 72 + c0 + j * 8]) = ph;
      *reinterpret_cast<ushort8*>(&fsl[sl * 72 + c0 + j * 8]) = pl;
    }
  }
  __syncthreads();

  const int l = tid & 63, w = tid >> 6;
  const int col = l & 15, g = l >> 4;

  bf16x8 bh[2][2], bl[2][2];
  #pragma unroll
  for (int ot = 0; ot < 2; ++ot)
    #pragma unroll
    for (int ks = 0; ks < 2; ++ks){
      int a = (w * 32 + ot * 16 + col) * 72 + ks * 32 + g * 8;
      bh[ot][ks] = *reinterpret_cast<const bf16x8*>(&wsh[a]);
      bl[ot][ks] = *reinterpret_cast<const bf16x8*>(&wsl[a]);
    }

  f32x4v acc[8][2];
  #pragma unroll
  for (int st = 0; st < 8; ++st)
    #pragma unroll
    for (int ot = 0; ot < 2; ++ot)
      acc[st][ot] = (f32x4v){0.f, 0.f, 0.f, 0.f};

  #pragma unroll
  for (int st = 0; st < 8; ++st){
    bf16x8 ah[2], al[2];
    #pragma unroll
    for (int ks = 0; ks < 2; ++ks){
      int a = (st * 16 + col) * 72 + ks * 32 + g * 8;
      ah[ks] = *reinterpret_cast<const bf16x8*>(&fsh[a]);
      al[ks] = *reinterpret_cast<const bf16x8*>(&fsl[a]);
    }
    #pragma unroll
    for (int ot = 0; ot < 2; ++ot){
      #pragma unroll
      for (int ks = 0; ks < 2; ++ks){
        acc[st][ot] = __builtin_amdgcn_mfma_f32_16x16x32_bf16(ah[ks], bh[ot][ks], acc[st][ot], 0, 0, 0);
        acc[st][ot] = __builtin_amdgcn_mfma_f32_16x16x32_bf16(ah[ks], bl[ot][ks], acc[st][ot], 0, 0, 0);
        acc[st][ot] = __builtin_amdgcn_mfma_f32_16x16x32_bf16(al[ks], bh[ot][ks], acc[st][ot], 0, 0, 0);
      }
    }
  }

  #pragma unroll
  for (int ot = 0; ot < 2; ++ot){
    const int ch = w * 32 + ot * 16 + col;
    float sv = 0.f, sq = 0.f;
    float mxm[4], mnm[4];
    #pragma unroll
    for (int j = 0; j < 4; ++j){ mxm[j] = -1e30f; mnm[j] = 1e30f; }
    #pragma unroll
    for (int st = 0; st < 8; ++st){
      f32x4v a = acc[st][ot];
      float t0 = a[0], t1 = a[1], t2 = a[2], t3 = a[3];
      sv += ((t0 + t1) + t2) + t3;
      sq += ((t0 * t0 + t1 * t1) + t2 * t2) + t3 * t3;
      float tmx = fmaxf(fmaxf(t0, t1), fmaxf(t2, t3));
      float tmn = fminf(fminf(t0, t1), fminf(t2, t3));
      mxm[st >> 1] = fmaxf(mxm[st >> 1], tmx);
      mnm[st >> 1] = fminf(mnm[st >> 1], tmn);
    }
    sv += __shfl_xor(sv, 16); sv += __shfl_xor(sv, 32);
    sq += __shfl_xor(sq, 16); sq += __shfl_xor(sq, 32);
    #pragma unroll
    for (int j = 0; j < 4; ++j){
      mxm[j] = fmaxf(mxm[j], __shfl_xor(mxm[j], 16));
      mxm[j] = fmaxf(mxm[j], __shfl_xor(mxm[j], 32));
      mnm[j] = fminf(mnm[j], __shfl_xor(mnm[j], 16));
      mnm[j] = fminf(mnm[j], __shfl_xor(mnm[j], 32));
    }
    if (g == 0){
      part[(size_t)(ch * 2) * 4096 + blk]     = sv;
      part[(size_t)(ch * 2 + 1) * 4096 + blk] = sq;
      #pragma unroll
      for (int j = 0; j < 4; ++j){
        size_t mf = (s0 >> 5) + j;
        mxmn[mf * 128 + ch]          = mxm[j];
        mxmn[MF_TOT + mf * 128 + ch] = mnm[j];
      }
    }
  }
}

// ---------------- BN stats reduce (legacy [ch*2][4096] partials) ------------
__global__ __launch_bounds__(256) void reduce_stats(const float* __restrict__ part,
                                                    const float* __restrict__ g,
                                                    const float* __restrict__ bb,
                                                    float* __restrict__ bn, int cout){
  const int ch = blockIdx.x, tid = threadIdx.x;
  float s = 0.f, q = 0.f;
  const float* ps = part + (size_t)(ch * 2) * 4096;
  const float* pq = part + (size_t)(ch * 2 + 1) * 4096;
  for (int i = tid; i < 4096; i += 256){ s += ps[i]; q += pq[i]; }
  #pragma unroll
  for (int off = 1; off < 64; off <<= 1){ s += __shfl_xor(s, off); q += __shfl_xor(q, off); }
  __shared__ float as_[4], aq_[4];
  if ((tid & 63) == 0){ as_[tid >> 6] = s; aq_[tid >> 6] = q; }
  __syncthreads();
  if (tid == 0){
    float S = as_[0] + as_[1] + as_[2] + as_[3];
    float Q = aq_[0] + aq_[1] + aq_[2] + aq_[3];
    const float cnt = 524288.0f;
    float mean = S / cnt;
    float var  = Q / cnt - mean * mean;
    float sc = g[ch] / sqrtf(var + 1e-5f);
    bn[ch] = sc;
    bn[cout + ch] = bb[ch] - mean * sc;
  }
}

// ---------------- finish: out = relu(max(a*mx+sh, a*mn+sh)) -----------------
__global__ __launch_bounds__(256) void bn_minmax_finish(const float* __restrict__ mxmn,
                                                        const float* __restrict__ bn2,
                                                        float* __restrict__ out){
  const int i = blockIdx.x * 256 + threadIdx.x;
  const int ch = i & 127;
  const float a = bn2[ch], sh = bn2[128 + ch];
  const float mx = mxmn[i], mn = mxmn[MF_TOT + i];
  out[i] = fmaxf(fmaxf(mx * a + sh, mn * a + sh), 0.0f);
}

extern "C" void kernel_launch(void* const* d_in, const int* in_sizes, int n_in,
                              void* d_out, int out_size, void* d_ws, size_t ws_size,
                              hipStream_t stream){
  (void)in_sizes; (void)n_in; (void)out_size; (void)ws_size;
  const float* xyz    = (const float*)d_in[0];
  const float* points = (const float*)d_in[1];
  const float* W0 = (const float*)d_in[2];
  const float* g0 = (const float*)d_in[3];
  const float* b0 = (const float*)d_in[4];
  const float* W1 = (const float*)d_in[5];
  const float* g1 = (const float*)d_in[6];
  const float* b1 = (const float*)d_in[7];
  const float* W2 = (const float*)d_in[8];
  const float* g2 = (const float*)d_in[9];
  const float* b2 = (const float*)d_in[10];

  float* out = (float*)d_out;
  float* o_newxyz = out;
  float* o_newpts = out + (size_t)B_ * M_ * 3;
  float* o_gind   = out + (size_t)B_ * M_ * 3 + (size_t)B_ * M_ * 128;

  char* ws = (char*)d_ws;
  int*   gi   = (int*)(ws + 0);                          // 2 MB
  float* part = (float*)(ws + (2ull << 20));             // 4 MB (layers 1/2)
  float* bn0  = (float*)(ws + (6ull << 20));
  float* bn1  = (float*)(ws + (6ull << 20) + 1024);
  float* bn2  = (float*)(ws + (6ull << 20) + 2048);
  float* phi  = (float*)(ws + (8ull << 20));             // 16 MB
  float* psi  = (float*)(ws + (24ull << 20));            // 4 MB
  unsigned short* h1 = (unsigned short*)(ws + (28ull << 20));   // 64 MB
  float* mxmn = (float*)(ws + (92ull << 20));            // 16 MB
  float* part0 = (float*)(ws + (108ull << 20));          // 8 MB (layer-0 stats)

  phi_kernel<<<512, 256, 0, stream>>>(xyz, points, W0, phi);
  fps_kernel<<<16, 256, 0, stream>>>(xyz, o_newxyz);
  ballq_stats_kernel<<<4160, 256, 0, stream>>>(xyz, o_newxyz, gi, o_gind,
                                               W0, psi, phi, part0);
  reduce_stats_rm<<<64, 256, 0, stream>>>(part0, g0, b0, bn0, 64);

  mlp1_mfma<<<4096, 256, 0, stream>>>(phi, psi, gi, bn0, W1, h1, part);
  reduce_stats<<<64, 256, 0, stream>>>(part, g1, b1, bn1, 64);

  mlp2_mfma<<<4096, 256, 0, stream>>>(h1, bn1, W2, part, mxmn);
  reduce_stats<<<128, 256, 0, stream>>>(part, g2, b2, bn2, 128);
  bn_minmax_finish<<<MF_TOT / 256, 256, 0, stream>>>(mxmn, bn2, o_newpts);
}

// Round 18
// 876.154 us; speedup vs baseline: 1.0290x; 1.0221x over previous
//
#include <hip/hip_runtime.h>
#include <hip/hip_bf16.h>
#include <cstdint>

#define B_ 16
#define N_ 4096
#define CPTS_ 64
#define M_ 1024
#define K_ 32
#define MF_TOT 2097152   // B_*M_*128 pooled outputs

using ushort8 = __attribute__((ext_vector_type(8))) unsigned short;
using bf16x8  = __attribute__((ext_vector_type(8))) short;
using f32x4v  = __attribute__((ext_vector_type(4))) float;

static __device__ __forceinline__ unsigned f2bf(float x){
  unsigned u = __float_as_uint(x);
  return (u + 0x7fffu + ((u >> 16) & 1u)) >> 16;   // RTNE
}
static __device__ __forceinline__ float bf2f(unsigned short u){
  return __uint_as_float(((unsigned)u) << 16);
}

// DPP max step: v = max(v, dpp_shift(v)). Values are >= 0 so 0-fill is identity.
#define DPPMAX(v, ctrl)                                                        \
  do {                                                                         \
    int _t = __builtin_amdgcn_update_dpp(0, __float_as_int(v), (ctrl), 0xf,    \
                                         0xf, true);                           \
    (v) = fmaxf((v), __int_as_float(_t));                                      \
  } while (0)

// One distance update, all indices compile-time constant (named float4 comps).
#define STEP(MD, PX, PY, PZ, C, J)                                             \
  { float dx = PX.C - cx, dy = PY.C - cy, dz = PZ.C - cz;                      \
    float d = dx * dx; d = d + dy * dy; d = d + dz * dz;                       \
    float nm = fminf(MD.C, d); MD.C = nm;                                      \
    if (nm > bv){ bv = nm; bj = (J); } }
#define STEP4(MD, PX, PY, PZ, J0)                                              \
  STEP(MD, PX, PY, PZ, x, J0)                                                  \
  STEP(MD, PX, PY, PZ, y, (J0) + 1)                                            \
  STEP(MD, PX, PY, PZ, z, (J0) + 2)                                            \
  STEP(MD, PX, PY, PZ, w, (J0) + 3)

// ---------------- FPS: 4 waves x 16 pts, u64-only 4-slot exchange -----------
// R14-proven floor (641 us). 7 structural variants tested; all others regress.
// Latency-bound: 1024 serial argmax iterations, ~1500 cy each (update issue +
// DPP reduce + barrier/exchange chain). Occupancy 0.75%, HBM ~0 by design.
__global__ __launch_bounds__(256, 1) void fps_kernel(const float* __restrict__ xyz,
                                                     float* __restrict__ newxyz){
#pragma clang fp contract(off)
  __shared__ float xs[N_], ys[N_], zs[N_];
  __shared__ int inds_s[M_];
  __shared__ unsigned long long sv_[2][4];
  const int b = blockIdx.x, tid = threadIdx.x;
  const int lane = tid & 63, wv = tid >> 6;
  const float* xb = xyz + (size_t)b * N_ * 3;
  for (int i = tid; i < N_ * 3; i += 256){
    float v = xb[i];
    int n = i / 3, c = i - n * 3;
    if (c == 0) xs[n] = v; else if (c == 1) ys[n] = v; else zs[n] = v;
  }
  __syncthreads();
  // per-lane points: n = tid*16 + j  (wave w owns [w*1024, w*1024+1024))
  const float4 px0 = *reinterpret_cast<const float4*>(&xs[tid * 16 + 0]);
  const float4 px1 = *reinterpret_cast<const float4*>(&xs[tid * 16 + 4]);
  const float4 px2 = *reinterpret_cast<const float4*>(&xs[tid * 16 + 8]);
  const float4 px3 = *reinterpret_cast<const float4*>(&xs[tid * 16 + 12]);
  const float4 py0 = *reinterpret_cast<const float4*>(&ys[tid * 16 + 0]);
  const float4 py1 = *reinterpret_cast<const float4*>(&ys[tid * 16 + 4]);
  const float4 py2 = *reinterpret_cast<const float4*>(&ys[tid * 16 + 8]);
  const float4 py3 = *reinterpret_cast<const float4*>(&ys[tid * 16 + 12]);
  const float4 pz0 = *reinterpret_cast<const float4*>(&zs[tid * 16 + 0]);
  const float4 pz1 = *reinterpret_cast<const float4*>(&zs[tid * 16 + 4]);
  const float4 pz2 = *reinterpret_cast<const float4*>(&zs[tid * 16 + 8]);
  const float4 pz3 = *reinterpret_cast<const float4*>(&zs[tid * 16 + 12]);
  float4 md0 = make_float4(1e10f, 1e10f, 1e10f, 1e10f);
  float4 md1 = md0, md2 = md0, md3 = md0;
  int far = 0;
  float cx = xs[0], cy = ys[0], cz = zs[0];
  for (int m = 0; m < M_; ++m){
    if (tid == 0) inds_s[m] = far;
    float bv = -1.0f; int bj = 0;
    STEP4(md0, px0, py0, pz0, 0)
    STEP4(md1, px1, py1, pz1, 4)
    STEP4(md2, px2, py2, pz2, 8)
    STEP4(md3, px3, py3, pz3, 12)
    // in-wave max via DPP (VALU, no LDS): result in lane 63
    float wm = bv;
    DPPMAX(wm, 0x111);  // row_shr:1
    DPPMAX(wm, 0x112);  // row_shr:2
    DPPMAX(wm, 0x114);  // row_shr:4
    DPPMAX(wm, 0x118);  // row_shr:8
    DPPMAX(wm, 0x142);  // row_bcast:15
    DPPMAX(wm, 0x143);  // row_bcast:31
    const float wmax = __int_as_float(
        __builtin_amdgcn_readlane(__float_as_int(wm), 63));
    // lowest tied lane = smallest n (lane ascending == n ascending per wave)
    unsigned long long tied = __ballot(bv == wmax);
    const int winlane = (int)__builtin_ctzll(tied);
    const int sl = m & 1;
    if (lane == winlane){
      int wn = tid * 16 + bj;
      sv_[sl][wv] = ((unsigned long long)__float_as_uint(wmax) << 32)
                  | (unsigned)(4095 - wn);     // (4095-n): smaller n wins on tie
    }
    __syncthreads();
    // 4-slot max tree; all pk distinct (distinct indices) => total order
    unsigned long long p0 = sv_[sl][0], p1 = sv_[sl][1], p2 = sv_[sl][2], p3 = sv_[sl][3];
    if (p1 > p0) p0 = p1;
    if (p3 > p2) p2 = p3;
    if (p2 > p0) p0 = p2;
    far = 4095 - (int)(p0 & 0xffffffffu);
    cx = xs[far]; cy = ys[far]; cz = zs[far];   // broadcast LDS reads
  }
  __syncthreads();
  for (int t = tid; t < M_; t += 256){
    int id = inds_s[t];
    size_t o = ((size_t)b * M_ + t) * 3;
    newxyz[o] = xs[id]; newxyz[o + 1] = ys[id]; newxyz[o + 2] = zs[id];
  }
}

// ---------------- phi: per-point layer-0 matmul (no gather) -----------------
__global__ __launch_bounds__(256) void phi_kernel(const float* __restrict__ xyz,
                                                  const float* __restrict__ points,
                                                  const float* __restrict__ W,
                                                  float* __restrict__ phi){
  __shared__ __align__(16) float Wt[67][64];
  __shared__ __align__(16) float ft[67][128];
  const int tid = threadIdx.x, blk = blockIdx.x;
  const int p0 = blk * 128;
  for (int i = tid; i < 67 * 64; i += 256){
    int o = i / 67, c = i - o * 67;
    Wt[c][o] = W[i];
  }
  const int sl = tid >> 1, half = tid & 1;
  const int p = p0 + sl;
  const float* ps = points + (size_t)p * CPTS_ + half * 32;
  #pragma unroll
  for (int j = 0; j < 8; ++j){
    float4 v = *reinterpret_cast<const float4*>(ps + j * 4);
    int c = 3 + half * 32 + j * 4;
    ft[c][sl] = v.x; ft[c + 1][sl] = v.y; ft[c + 2][sl] = v.z; ft[c + 3][sl] = v.w;
  }
  if (half == 0){
    const float* xp = xyz + (size_t)p * 3;
    ft[0][sl] = xp[0]; ft[1][sl] = xp[1]; ft[2][sl] = xp[2];
  }
  __syncthreads();
  const int sg = tid & 31, og = tid >> 5;
  float acc[4][8];
  #pragma unroll
  for (int i = 0; i < 4; ++i)
    #pragma unroll
    for (int o = 0; o < 8; ++o) acc[i][o] = 0.0f;
  #pragma unroll 2
  for (int c = 0; c < 67; ++c){
    float4 f = *reinterpret_cast<const float4*>(&ft[c][sg * 4]);
    float4 w0 = *reinterpret_cast<const float4*>(&Wt[c][og * 8]);
    float4 w1 = *reinterpret_cast<const float4*>(&Wt[c][og * 8 + 4]);
    const float fv[4] = {f.x, f.y, f.z, f.w};
    #pragma unroll
    for (int i = 0; i < 4; ++i){
      acc[i][0] += fv[i] * w0.x; acc[i][1] += fv[i] * w0.y;
      acc[i][2] += fv[i] * w0.z; acc[i][3] += fv[i] * w0.w;
      acc[i][4] += fv[i] * w1.x; acc[i][5] += fv[i] * w1.y;
      acc[i][6] += fv[i] * w1.z; acc[i][7] += fv[i] * w1.w;
    }
  }
  #pragma unroll
  for (int i = 0; i < 4; ++i){
    float* dst = phi + (size_t)(p0 + sg * 4 + i) * 64 + og * 8;
    *reinterpret_cast<float4*>(dst)     = make_float4(acc[i][0], acc[i][1], acc[i][2], acc[i][3]);
    *reinterpret_cast<float4*>(dst + 4) = make_float4(acc[i][4], acc[i][5], acc[i][6], acc[i][7]);
  }
}

// ---------------- Ball query (blocks 0..4095) + psi (blocks 4096..4159) -----
__global__ __launch_bounds__(256) void ballq_psi_kernel(const float* __restrict__ xyz,
                                                        const float* __restrict__ newxyz,
                                                        int* __restrict__ gi,
                                                        float* __restrict__ gif,
                                                        const float* __restrict__ W0,
                                                        float* __restrict__ psi){
  if (blockIdx.x >= 4096){
    const int mi = (blockIdx.x - 4096) * 256 + threadIdx.x;
    const float x = newxyz[(size_t)mi * 3];
    const float y = newxyz[(size_t)mi * 3 + 1];
    const float z = newxyz[(size_t)mi * 3 + 2];
    float* dst = psi + (size_t)mi * 64;
    #pragma unroll
    for (int o4 = 0; o4 < 16; ++o4){
      float v[4];
      #pragma unroll
      for (int e = 0; e < 4; ++e){
        int o = o4 * 4 + e;
        v[e] = fmaf(z, W0[o * 67 + 2], fmaf(y, W0[o * 67 + 1], x * W0[o * 67]));
      }
      *reinterpret_cast<float4*>(dst + o4 * 4) = make_float4(v[0], v[1], v[2], v[3]);
    }
    return;
  }
  const int gw = (blockIdx.x * 256 + threadIdx.x) >> 6;
  const int lane = threadIdx.x & 63;
  const int b = gw >> 10, m = gw & 1023;
  const float* xb = xyz + (size_t)b * N_ * 3;
  const size_t no = (size_t)b * M_ + m;
  const float cx = newxyz[no * 3], cy = newxyz[no * 3 + 1], cz = newxyz[no * 3 + 2];
  const float sm = fmaf(cz, cz, fmaf(cy, cy, cx * cx));
  int total = 0, first_idx = 0; bool havef = false;
  int*   gd = gi  + no * K_;
  float* fd = gif + no * K_;
  for (int ch = 0; ch < 64 && total < K_; ++ch){
    const int n = ch * 64 + lane;
    const float x = xb[n * 3], y = xb[n * 3 + 1], z = xb[n * 3 + 2];
    const float sn = fmaf(z, z, fmaf(y, y, x * x));
    const float dt = fmaf(z, cz, fmaf(y, cy, x * cx));
    float d2 = (sm + sn) - 2.0f * dt;                 // ref: |a|^2+|b|^2-2ab
    float dist = sqrtf(fmaxf(d2, 0.0f));
    bool pred = !(dist > 0.2f);
    unsigned long long mask = __ballot(pred);
    if (!havef && mask){ havef = true; first_idx = ch * 64 + (int)__builtin_ctzll(mask); }
    if (pred){
      int rank = total + (int)__popcll(mask & ((1ull << lane) - 1ull));
      if (rank < K_){ gd[rank] = n; fd[rank] = (float)n; }
    }
    total += (int)__popcll(mask);
  }
  if (total < K_ && lane >= total && lane < K_){ gd[lane] = first_idx; fd[lane] = (float)first_idx; }
}

// ---------------- stats0: BN0 sums over gathered (phi - psi) ----------------
__global__ __launch_bounds__(256) void stats0_kernel(const float* __restrict__ phi,
                                                     const float* __restrict__ psi,
                                                     const int* __restrict__ gi,
                                                     float* __restrict__ part){
  __shared__ int gidx[128];
  __shared__ float psm[4][64];
  const int tid = threadIdx.x, blk = blockIdx.x;
  const size_t s0 = (size_t)blk * 128;
  const int b  = (int)(s0 >> 15);
  const int m0 = ((int)(s0 & 32767)) >> 5;
  if (tid < 128) gidx[tid] = gi[(size_t)b * 32768 + (size_t)m0 * K_ + tid];
  psm[tid >> 6][tid & 63] =
      psi[((size_t)b * M_ + m0 + (tid >> 6)) * 64 + (tid & 63)];
  __syncthreads();
  const int sg = tid & 31, og = tid >> 5;
  const int mi = sg >> 3;
  float sv[8], sq[8];
  #pragma unroll
  for (int o = 0; o < 8; ++o){ sv[o] = 0.f; sq[o] = 0.f; }
  #pragma unroll
  for (int i = 0; i < 4; ++i){
    const int g = gidx[sg * 4 + i];
    const float* gp = phi + ((size_t)b * N_ + g) * 64 + og * 8;
    float4 a0 = *reinterpret_cast<const float4*>(gp);
    float4 a1 = *reinterpret_cast<const float4*>(gp + 4);
    const float pv[8] = {a0.x, a0.y, a0.z, a0.w, a1.x, a1.y, a1.z, a1.w};
    #pragma unroll
    for (int o = 0; o < 8; ++o){
      float v = pv[o] - psm[mi][og * 8 + o];
      sv[o] += v; sq[o] += v * v;
    }
  }
  #pragma unroll
  for (int off = 1; off < 32; off <<= 1){
    #pragma unroll
    for (int o = 0; o < 8; ++o){
      sv[o] += __shfl_xor(sv[o], off);
      sq[o] += __shfl_xor(sq[o], off);
    }
  }
  if (sg == 0){
    #pragma unroll
    for (int o = 0; o < 8; ++o){
      int ch = og * 8 + o;
      part[(size_t)(ch * 2) * 4096 + blk]     = sv[o];
      part[(size_t)(ch * 2 + 1) * 4096 + blk] = sq[o];
    }
  }
}

// ---------------- mlp1 via MFMA (split-bf16, 3-term) — R13-verified ---------
__global__ __launch_bounds__(256) void mlp1_mfma(
    const float* __restrict__ phi, const float* __restrict__ psi,
    const int* __restrict__ gi, const float* __restrict__ bn0,
    const float* __restrict__ W1,
    unsigned short* __restrict__ h1, float* __restrict__ part)
{
  __shared__ unsigned short wsh[64 * 72], wsl[64 * 72];
  __shared__ unsigned short fsh[128 * 72], fsl[128 * 72];
  __shared__ int gidx[128];
  __shared__ float psm[4][64];
  const int tid = threadIdx.x, blk = blockIdx.x;
  const size_t s0 = (size_t)blk * 128;
  const int b  = (int)(s0 >> 15);
  const int m0 = ((int)(s0 & 32767)) >> 5;

  for (int i = tid; i < 64 * 64; i += 256){
    int o = i >> 6, c = i & 63;
    float f = W1[i];
    unsigned hb = f2bf(f);
    float res = f - bf2f((unsigned short)hb);
    wsh[o * 72 + c] = (unsigned short)hb;
    wsl[o * 72 + c] = (unsigned short)f2bf(res);
  }
  if (tid < 128) gidx[tid] = gi[(size_t)b * 32768 + (size_t)m0 * K_ + tid];
  psm[tid >> 6][tid & 63] =
      psi[((size_t)b * M_ + m0 + (tid >> 6)) * 64 + (tid & 63)];
  __syncthreads();
  {
    const int sl = tid >> 1, half = tid & 1;
    const int g = gidx[sl];
    const int mi = sl >> 5;
    const float* gp = phi + ((size_t)b * N_ + g) * 64 + half * 32;
    #pragma unroll
    for (int jj = 0; jj < 4; ++jj){
      float4 v0 = *reinterpret_cast<const float4*>(gp + jj * 8);
      float4 v1 = *reinterpret_cast<const float4*>(gp + jj * 8 + 4);
      const float vv[8] = {v0.x, v0.y, v0.z, v0.w, v1.x, v1.y, v1.z, v1.w};
      ushort8 ph, pl;
      #pragma unroll
      for (int e = 0; e < 8; ++e){
        int c = half * 32 + jj * 8 + e;
        float f = fmaxf((vv[e] - psm[mi][c]) * bn0[c] + bn0[64 + c], 0.0f);
        unsigned hb = f2bf(f);
        float res = f - bf2f((unsigned short)hb);
        ph[e] = (unsigned short)hb;
        pl[e] = (unsigned short)f2bf(res);
      }
      *reinterpret_cast<ushort8*>(&fsh[sl * 72 + half * 32 + jj * 8]) = ph;
      *reinterpret_cast<ushort8*>(&fsl[sl * 72 + half * 32 + jj * 8]) = pl;
    }
  }
  __syncthreads();

  const int l = tid & 63, w = tid >> 6;
  const int col = l & 15, g4 = l >> 4;
  const int ch = w * 16 + col;

  bf16x8 bh[2], bl[2];
  #pragma unroll
  for (int ks = 0; ks < 2; ++ks){
    int a = ch * 72 + ks * 32 + g4 * 8;
    bh[ks] = *reinterpret_cast<const bf16x8*>(&wsh[a]);
    bl[ks] = *reinterpret_cast<const bf16x8*>(&wsl[a]);
  }

  f32x4v acc[8];
  #pragma unroll
  for (int st = 0; st < 8; ++st) acc[st] = (f32x4v){0.f, 0.f, 0.f, 0.f};

  #pragma unroll
  for (int st = 0; st < 8; ++st){
    #pragma unroll
    for (int ks = 0; ks < 2; ++ks){
      int a = (st * 16 + col) * 72 + ks * 32 + g4 * 8;
      bf16x8 ah = *reinterpret_cast<const bf16x8*>(&fsh[a]);
      bf16x8 al = *reinterpret_cast<const bf16x8*>(&fsl[a]);
      acc[st] = __builtin_amdgcn_mfma_f32_16x16x32_bf16(ah, bh[ks], acc[st], 0, 0, 0);
      acc[st] = __builtin_amdgcn_mfma_f32_16x16x32_bf16(ah, bl[ks], acc[st], 0, 0, 0);
      acc[st] = __builtin_amdgcn_mfma_f32_16x16x32_bf16(al, bh[ks], acc[st], 0, 0, 0);
    }
  }

  #pragma unroll
  for (int st = 0; st < 8; ++st){
    size_t sbase = s0 + st * 16 + g4 * 4;
    #pragma unroll
    for (int r = 0; r < 4; ++r)
      h1[(sbase + r) * 64 + ch] = (unsigned short)f2bf(acc[st][r]);
  }

  float sv = 0.f, sq = 0.f;
  #pragma unroll
  for (int st = 0; st < 8; ++st){
    f32x4v a = acc[st];
    float t0 = a[0], t1 = a[1], t2 = a[2], t3 = a[3];
    sv += ((t0 + t1) + t2) + t3;
    sq += ((t0 * t0 + t1 * t1) + t2 * t2) + t3 * t3;
  }
  sv += __shfl_xor(sv, 16); sv += __shfl_xor(sv, 32);
  sq += __shfl_xor(sq, 16); sq += __shfl_xor(sq, 32);
  if (g4 == 0){
    part[(size_t)(ch * 2) * 4096 + blk]     = sv;
    part[(size_t)(ch * 2 + 1) * 4096 + blk] = sq;
  }
}

// ---------------- mlp2 via MFMA (split-bf16, 3-term) — R12-verified ---------
__global__ __launch_bounds__(256) void mlp2_mfma(
    const unsigned short* __restrict__ h1, const float* __restrict__ bn1,
    const float* __restrict__ W2, float* __restrict__ part,
    float* __restrict__ mxmn)
{
  __shared__ unsigned short wsh[128 * 72], wsl[128 * 72];
  __shared__ unsigned short fsh[128 * 72], fsl[128 * 72];
  const int tid = threadIdx.x, blk = blockIdx.x;
  const size_t s0 = (size_t)blk * 128;

  for (int i = tid; i < 128 * 64; i += 256){
    int o = i >> 6, c = i & 63;
    float f = W2[i];
    unsigned hb = f2bf(f);
    float res = f - bf2f((unsigned short)hb);
    wsh[o * 72 + c] = (unsigned short)hb;
    wsl[o * 72 + c] = (unsigned short)f2bf(res);
  }
  {
    const int sl = tid >> 1, c0 = (tid & 1) * 32;
    const unsigned short* hp = h1 + (s0 + sl) * 64 + c0;
    #pragma unroll
    for (int j = 0; j < 4; ++j){
      ushort8 raw = *reinterpret_cast<const ushort8*>(hp + j * 8);
      ushort8 ph, pl;
      #pragma unroll
      for (int e = 0; e < 8; ++e){
        int c = c0 + j * 8 + e;
        float f = fmaxf(bf2f(raw[e]) * bn1[c] + bn1[64 + c], 0.0f);
        unsigned hb = f2bf(f);
        float res = f - bf2f((unsigned short)hb);
        ph[e] = (unsigned short)hb;
        pl[e] = (unsigned short)f2bf(res);
      }
      *reinterpret_cast<ushort8*>(&fsh[sl * 72 + c0 + j * 8]) = ph;
      *reinterpret_cast<ushort8*>(&fsl[sl * 72 + c0 + j * 8]) = pl;
    }
  }
  __syncthreads();

  const int l = tid & 63, w = tid >> 6;
  const int col = l & 15, g = l >> 4;

  bf16x8 bh[2][2], bl[2][2];
  #pragma unroll
  for (int ot = 0; ot < 2; ++ot)
    #pragma unroll
    for (int ks = 0; ks < 2; ++ks){
      int a = (w * 32 + ot * 16 + col) * 72 + ks * 32 + g * 8;
      bh[ot][ks] = *reinterpret_cast<const bf16x8*>(&wsh[a]);
      bl[ot][ks] = *reinterpret_cast<const bf16x8*>(&wsl[a]);
    }

  f32x4v acc[8][2];
  #pragma unroll
  for (int st = 0; st < 8; ++st)
    #pragma unroll
    for (int ot = 0; ot < 2; ++ot)
      acc[st][ot] = (f32x4v){0.f, 0.f, 0.f, 0.f};

  #pragma unroll
  for (int st = 0; st < 8; ++st){
    bf16x8 ah[2], al[2];
    #pragma unroll
    for (int ks = 0; ks < 2; ++ks){
      int a = (st * 16 + col) * 72 + ks * 32 + g * 8;
      ah[ks] = *reinterpret_cast<const bf16x8*>(&fsh[a]);
      al[ks] = *reinterpret_cast<const bf16x8*>(&fsl[a]);
    }
    #pragma unroll
    for (int ot = 0; ot < 2; ++ot){
      #pragma unroll
      for (int ks = 0; ks < 2; ++ks){
        acc[st][ot] = __builtin_amdgcn_mfma_f32_16x16x32_bf16(ah[ks], bh[ot][ks], acc[st][ot], 0, 0, 0);
        acc[st][ot] = __builtin_amdgcn_mfma_f32_16x16x32_bf16(ah[ks], bl[ot][ks], acc[st][ot], 0, 0, 0);
        acc[st][ot] = __builtin_amdgcn_mfma_f32_16x16x32_bf16(al[ks], bh[ot][ks], acc[st][ot], 0, 0, 0);
      }
    }
  }

  #pragma unroll
  for (int ot = 0; ot < 2; ++ot){
    const int ch = w * 32 + ot * 16 + col;
    float sv = 0.f, sq = 0.f;
    float mxm[4], mnm[4];
    #pragma unroll
    for (int j = 0; j < 4; ++j){ mxm[j] = -1e30f; mnm[j] = 1e30f; }
    #pragma unroll
    for (int st = 0; st < 8; ++st){
      f32x4v a = acc[st][ot];
      float t0 = a[0], t1 = a[1], t2 = a[2], t3 = a[3];
      sv += ((t0 + t1) + t2) + t3;
      sq += ((t0 * t0 + t1 * t1) + t2 * t2) + t3 * t3;
      float tmx = fmaxf(fmaxf(t0, t1), fmaxf(t2, t3));
      float tmn = fminf(fminf(t0, t1), fminf(t2, t3));
      mxm[st >> 1] = fmaxf(mxm[st >> 1], tmx);
      mnm[st >> 1] = fminf(mnm[st >> 1], tmn);
    }
    sv += __shfl_xor(sv, 16); sv += __shfl_xor(sv, 32);
    sq += __shfl_xor(sq, 16); sq += __shfl_xor(sq, 32);
    #pragma unroll
    for (int j = 0; j < 4; ++j){
      mxm[j] = fmaxf(mxm[j], __shfl_xor(mxm[j], 16));
      mxm[j] = fmaxf(mxm[j], __shfl_xor(mxm[j], 32));
      mnm[j] = fminf(mnm[j], __shfl_xor(mnm[j], 16));
      mnm[j] = fminf(mnm[j], __shfl_xor(mnm[j], 32));
    }
    if (g == 0){
      part[(size_t)(ch * 2) * 4096 + blk]     = sv;
      part[(size_t)(ch * 2 + 1) * 4096 + blk] = sq;
      #pragma unroll
      for (int j = 0; j < 4; ++j){
        size_t mf = (s0 >> 5) + j;
        mxmn[mf * 128 + ch]          = mxm[j];
        mxmn[MF_TOT + mf * 128 + ch] = mnm[j];
      }
    }
  }
}

// ---------------- BN stats reduce + scale/shift -----------------------------
__global__ __launch_bounds__(256) void reduce_stats(const float* __restrict__ part,
                                                    const float* __restrict__ g,
                                                    const float* __restrict__ bb,
                                                    float* __restrict__ bn, int cout){
  const int ch = blockIdx.x, tid = threadIdx.x;
  float s = 0.f, q = 0.f;
  const float* ps = part + (size_t)(ch * 2) * 4096;
  const float* pq = part + (size_t)(ch * 2 + 1) * 4096;
  for (int i = tid; i < 4096; i += 256){ s += ps[i]; q += pq[i]; }
  #pragma unroll
  for (int off = 1; off < 64; off <<= 1){ s += __shfl_xor(s, off); q += __shfl_xor(q, off); }
  __shared__ float as_[4], aq_[4];
  if ((tid & 63) == 0){ as_[tid >> 6] = s; aq_[tid >> 6] = q; }
  __syncthreads();
  if (tid == 0){
    float S = as_[0] + as_[1] + as_[2] + as_[3];
    float Q = aq_[0] + aq_[1] + aq_[2] + aq_[3];
    const float cnt = 524288.0f;
    float mean = S / cnt;
    float var  = Q / cnt - mean * mean;
    float sc = g[ch] / sqrtf(var + 1e-5f);
    bn[ch] = sc;
    bn[cout + ch] = bb[ch] - mean * sc;
  }
}

// ---------------- finish: out = relu(max(a*mx+sh, a*mn+sh)) -----------------
__global__ __launch_bounds__(256) void bn_minmax_finish(const float* __restrict__ mxmn,
                                                        const float* __restrict__ bn2,
                                                        float* __restrict__ out){
  const int i = blockIdx.x * 256 + threadIdx.x;
  const int ch = i & 127;
  const float a = bn2[ch], sh = bn2[128 + ch];
  const float mx = mxmn[i], mn = mxmn[MF_TOT + i];
  out[i] = fmaxf(fmaxf(mx * a + sh, mn * a + sh), 0.0f);
}

extern "C" void kernel_launch(void* const* d_in, const int* in_sizes, int n_in,
                              void* d_out, int out_size, void* d_ws, size_t ws_size,
                              hipStream_t stream){
  (void)in_sizes; (void)n_in; (void)out_size; (void)ws_size;
  const float* xyz    = (const float*)d_in[0];
  const float* points = (const float*)d_in[1];
  const float* W0 = (const float*)d_in[2];
  const float* g0 = (const float*)d_in[3];
  const float* b0 = (const float*)d_in[4];
  const float* W1 = (const float*)d_in[5];
  const float* g1 = (const float*)d_in[6];
  const float* b1 = (const float*)d_in[7];
  const float* W2 = (const float*)d_in[8];
  const float* g2 = (const float*)d_in[9];
  const float* b2 = (const float*)d_in[10];

  float* out = (float*)d_out;
  float* o_newxyz = out;
  float* o_newpts = out + (size_t)B_ * M_ * 3;
  float* o_gind   = out + (size_t)B_ * M_ * 3 + (size_t)B_ * M_ * 128;

  char* ws = (char*)d_ws;
  int*   gi   = (int*)(ws + 0);                          // 2 MB
  float* part = (float*)(ws + (2ull << 20));             // 4 MB
  float* bn0  = (float*)(ws + (6ull << 20));
  float* bn1  = (float*)(ws + (6ull << 20) + 1024);
  float* bn2  = (float*)(ws + (6ull << 20) + 2048);
  float* phi  = (float*)(ws + (8ull << 20));             // 16 MB
  float* psi  = (float*)(ws + (24ull << 20));            // 4 MB
  unsigned short* h1 = (unsigned short*)(ws + (28ull << 20));   // 64 MB
  float* mxmn = (float*)(ws + (92ull << 20));            // 16 MB

  phi_kernel<<<512, 256, 0, stream>>>(xyz, points, W0, phi);
  fps_kernel<<<16, 256, 0, stream>>>(xyz, o_newxyz);
  ballq_psi_kernel<<<4160, 256, 0, stream>>>(xyz, o_newxyz, gi, o_gind, W0, psi);

  stats0_kernel<<<4096, 256, 0, stream>>>(phi, psi, gi, part);
  reduce_stats<<<64, 256, 0, stream>>>(part, g0, b0, bn0, 64);

  mlp1_mfma<<<4096, 256, 0, stream>>>(phi, psi, gi, bn0, W1, h1, part);
  reduce_stats<<<64, 256, 0, stream>>>(part, g1, b1, bn1, 64);

  mlp2_mfma<<<4096, 256, 0, stream>>>(h1, bn1, W2, part, mxmn);
  reduce_stats<<<128, 256, 0, stream>>>(part, g2, b2, bn2, 128);
  bn_minmax_finish<<<MF_TOT / 256, 256, 0, stream>>>(mxmn, bn2, o_newpts);
}